// Round 1
// 628.815 us; speedup vs baseline: 1.0387x; 1.0387x over previous
//
#include <hip/hip_runtime.h>
#include <hip/hip_bf16.h>

// Problem: VOCAB=30522, TYPES=2, D0=64, D1=768, D2=64, MAXOFF=64, GLOB=64,
// B=8, S=512, EPS=1e-12.
//
// ESTABLISHED (R0-R5 prior session + R6 this session):
//  * Inputs: FP32, setup_inputs() dict order. Outputs: FP32 buffer, compared
//    after bf16 quantization (threshold 0.103). R4 passed, absmax 0.0078.
//  * dur_us includes one harness 0xAA poison fill (~350us, 2.2GB) -> our 4
//    kernels account for the remaining ~300us. Roofline for them is ~145us:
//    embd2 stream ~90us, embd1 ~15us, small ~5us.
//  * R6 theory: k_diagmm was the gap — 256 blocks = 1 wave/SIMD, serial LDS
//    chain + 12 barrier/staging rounds, latency fully exposed. Rewritten:
//    512 blocks (2/CU), barrier-free K-loop, W_diag pre-transposed to a
//    float4 table read straight from L2, raw rows staged once as b128
//    broadcasts.
#define S_ 512
#define D1_ 768

typedef unsigned int v4u __attribute__((ext_vector_type(4)));

// out layout (fp32 elements, concatenated in return order):
//   embd0 [8,64,64]      at 0        (32768)
//   embd1 [8,512,768]    at 32768    (3145728)
//   embd2 [8,512,512,64] at 3178496  (134217728)

__device__ __forceinline__ float wsum(float v) {
#pragma unroll
    for (int o = 32; o; o >>= 1) v += __shfl_xor(v, o);
    return v;
}

// ---------------------------------------------------------------------------
// K0: blocks 0..63   -> embd0 = LN(W_glob) broadcast to 8 batches
//     blocks 64..193 -> 130-row LN'd W_rel table (fp32) in ws
//     blocks 194..385-> W_diag transpose: wdT4[g][c] = Wd[c][4g..4g+3]
//                       (float4 layout [192][64] so k_diagmm's K-loop reads
//                        1KB/wave coalesced from L2, no LDS staging needed)
__global__ __launch_bounds__(64) void k_small(const float* __restrict__ Wg,
                                              const float* __restrict__ Wr,
                                              const float* __restrict__ Wd,
                                              float* __restrict__ out0,
                                              float* __restrict__ table,
                                              float4* __restrict__ wdT4) {
    int t = threadIdx.x;
    int bid = blockIdx.x;
    if (bid >= 194) {
        int g = bid - 194;  // 0..191 : kk block = 4g..4g+3
        // per-lane 16B load, stride 768 floats between lanes (L2 absorbs),
        // store fully coalesced.
        float4 v = *(const float4*)(Wd + (size_t)t * D1_ + 4 * g);
        wdT4[g * 64 + t] = v;
        return;
    }
    float v = (bid < 64) ? Wg[bid * 64 + t] : Wr[(bid - 64) * 64 + t];
    float m = wsum(v) * (1.f / 64.f);
    float d = v - m;
    float q = wsum(d * d) * (1.f / 64.f);
    float o = d * rsqrtf(q + 1e-12f);
    if (bid < 64) {
#pragma unroll
        for (int b = 0; b < 8; b++) out0[b * 4096 + bid * 64 + t] = o;
    } else {
        table[(bid - 64) * 64 + t] = o;
    }
}

// ---------------------------------------------------------------------------
// K1: one block per (b,s). raw = W_word[tok]+W_type[ty]+W_abs[s]; out1 =
// LN(raw) fp32; raw also stored fp32 to ws for the diag matmul kernel.
__global__ __launch_bounds__(256) void k_embd1(const int* __restrict__ tok,
                                               const int* __restrict__ tty,
                                               const float* __restrict__ Ww,
                                               const float* __restrict__ Wt,
                                               const float* __restrict__ Wa,
                                               float* __restrict__ out1,
                                               float* __restrict__ rawout) {
    __shared__ float ssum[4], ssq[4];
    int t = threadIdx.x;
    int bs = blockIdx.x;  // b*512 + s
    int s = bs & (S_ - 1);
    size_t wrow = (size_t)tok[bs] * D1_;
    int trow = tty[bs] * D1_;
    int arow = s * D1_;
    float v0 = Ww[wrow + t]       + Wt[trow + t]       + Wa[arow + t];
    float v1 = Ww[wrow + t + 256] + Wt[trow + t + 256] + Wa[arow + t + 256];
    float v2 = Ww[wrow + t + 512] + Wt[trow + t + 512] + Wa[arow + t + 512];
    float ls = v0 + v1 + v2;
    float lq = v0 * v0 + v1 * v1 + v2 * v2;
    float s1 = wsum(ls), q1 = wsum(lq);
    int w = t >> 6;
    if ((t & 63) == 0) { ssum[w] = s1; ssq[w] = q1; }
    __syncthreads();
    float Sa = ssum[0] + ssum[1] + ssum[2] + ssum[3];
    float Qa = ssq[0] + ssq[1] + ssq[2] + ssq[3];
    float mean = Sa * (1.f / 768.f);
    float var = Qa * (1.f / 768.f) - mean * mean;
    float rstd = rsqrtf(var + 1e-12f);
    size_t ob = (size_t)bs * D1_;
    out1[ob + t]       = (v0 - mean) * rstd;
    out1[ob + t + 256] = (v1 - mean) * rstd;
    out1[ob + t + 512] = (v2 - mean) * rstd;
    rawout[ob + t] = v0;
    rawout[ob + t + 256] = v1;
    rawout[ob + t + 512] = v2;
}

// ---------------------------------------------------------------------------
// K1b (R6 rewrite): diag2 = raw[4096,768] @ Wd[64,768]^T + bd, fused with
// LN(W_rel[0] + diag2) -> diagLN[4096,64].
// 512 blocks x 256 threads, 8 rows/block, 2 outputs/thread (rows rq, rq+4).
// raw rows staged ONCE in LDS (24KB, b128 broadcast reads); W read as the
// pre-transposed wdT4 table straight from L2, 1KB/wave coalesced. No barrier
// in the K-loop -> latency hidden by 8 waves/CU instead of exposed at 1
// wave/SIMD like the old 256-block tiled version.
__global__ __launch_bounds__(256) void k_diagmm(const float* __restrict__ rawS,
                                                const float4* __restrict__ wdT4,
                                                const float* __restrict__ bd,
                                                const float* __restrict__ Wr,
                                                float* __restrict__ diagLN) {
    __shared__ float rawT[8 * D1_];  // 24 KB
    int t = threadIdx.x;
    int r0 = blockIdx.x * 8;
    for (int x = t; x < 8 * D1_; x += 256)
        rawT[x] = rawS[(size_t)r0 * D1_ + x];
    __syncthreads();
    int c = t & 63, rq = t >> 6;   // col, wave id (wave-uniform)
    const float4* ra4 = (const float4*)&rawT[rq * D1_];        // row rq
    const float4* rb4 = (const float4*)&rawT[(rq + 4) * D1_];  // row rq+4
    float a0 = 0.f, a1 = 0.f;
#pragma unroll 4
    for (int g = 0; g < 192; g++) {
        float4 w = wdT4[g * 64 + c];  // coalesced, L2-hot
        float4 x = ra4[g];            // ds_read_b128 broadcast
        float4 y = rb4[g];
        a0 += x.x * w.x + x.y * w.y + x.z * w.z + x.w * w.w;
        a1 += y.x * w.x + y.y * w.y + y.z * w.z + y.w * w.w;
    }
    float base = bd[c] + Wr[c];  // bias + W_rel row 0 (diagonal base embd)
    {
        float v = a0 + base;
        float mean = wsum(v) * (1.f / 64.f);
        float d = v - mean;
        float q = wsum(d * d) * (1.f / 64.f);
        diagLN[(r0 + rq) * 64 + c] = d * rsqrtf(q + 1e-12f);
    }
    {
        float v = a1 + base;
        float mean = wsum(v) * (1.f / 64.f);
        float d = v - mean;
        float q = wsum(d * d) * (1.f / 64.f);
        diagLN[(r0 + rq + 4) * 64 + c] = d * rsqrtf(q + 1e-12f);
    }
}

// ---------------------------------------------------------------------------
// K2: embd2 streamer. One block per (b,i); groups of 16 lanes copy one 256B
// fp32 row per j: the LN'd table row picked by the rpe id, or the fused
// diagLN row when j==i. Nontemporal stores (536MB pure stream, never re-read).
// id: diag->diagLN; (i==0,j>0)->128; (i>0,j==0)->129; diff-type->64;
// d=i-j>0 -> 128-min(d,63); d<0 -> min(-d,63).
__global__ __launch_bounds__(256) void k_embd2(const int* __restrict__ tty,
                                               const v4u* __restrict__ table,
                                               const v4u* __restrict__ diagLN,
                                               v4u* __restrict__ out2) {
    __shared__ int ty[S_];
    int t = threadIdx.x;
    int bi = blockIdx.x;  // b*512 + i
    int b = bi >> 9, i = bi & (S_ - 1);
    for (int j = t; j < S_; j += 256) ty[j] = tty[b * S_ + j];
    __syncthreads();
    int ti = ty[i];
    int sub = t & 15;       // 16 v4u per 64-fp32 row
    int jbase = t >> 4;     // 16 rows per pass
    size_t obase = (size_t)bi * (S_ * 16);  // v4u index of (b,i,j=0)
    const v4u* drow = diagLN + (size_t)bi * 16;
#pragma unroll 8
    for (int it = 0; it < 32; it++) {
        int j = it * 16 + jbase;
        int d = i - j;
        const v4u* src;
        if (d == 0)           src = drow;               // diagonal (incl. 0,0)
        else if (i == 0)      src = table + 128 * 16;   // row 0, j>0
        else if (j == 0)      src = table + 129 * 16;   // col 0, i>0
        else if (ty[j] != ti) src = table + 64 * 16;    // cross-segment
        else if (d > 0)       src = table + (128 - (d < 63 ? d : 63)) * 16;
        else { int nd = -d;   src = table + (nd < 63 ? nd : 63) * 16; }
        __builtin_nontemporal_store(src[sub], &out2[obase + (size_t)j * 16 + sub]);
    }
}

extern "C" void kernel_launch(void* const* d_in, const int* in_sizes, int n_in,
                              void* d_out, int out_size, void* d_ws, size_t ws_size,
                              hipStream_t stream) {
    // Dict order (confirmed R3/R4): tok(4096) tty(4096) Ww(23440896) Wt(1536)
    // Wa(393216) Wr(8320) Wg(4096) Wd(49152) bd(64).
    const int* tok  = (const int*)d_in[0];
    const int* tty  = (const int*)d_in[1];
    const float* Ww = (const float*)d_in[2];
    const float* Wt = (const float*)d_in[3];
    const float* Wa = (const float*)d_in[4];
    const float* Wr = (const float*)d_in[5];
    const float* Wg = (const float*)d_in[6];
    const float* Wd = (const float*)d_in[7];
    const float* bd = (const float*)d_in[8];

    float* out  = (float*)d_out;
    float* out0 = out;
    float* out1 = out + 32768;
    float* out2 = out + 3178496;

    // ws: table fp32 @0 (33,280B); diagLN fp32 @65536 (1MB); wdT4 @1114112
    // (192KB, fits in the diagLN..raw gap); raw fp32 @2097152 (12.6MB).
    // Total ~14.7MB (unchanged footprint vs R4).
    float* table  = (float*)d_ws;
    float* diagLN = (float*)((char*)d_ws + 65536);
    float4* wdT4  = (float4*)((char*)d_ws + 1114112);
    float* rawws  = (float*)((char*)d_ws + 2097152);

    hipLaunchKernelGGL(k_small, dim3(386), dim3(64), 0, stream,
                       Wg, Wr, Wd, out0, table, wdT4);
    hipLaunchKernelGGL(k_embd1, dim3(4096), dim3(256), 0, stream,
                       tok, tty, Ww, Wt, Wa, out1, rawws);
    hipLaunchKernelGGL(k_diagmm, dim3(512), dim3(256), 0, stream,
                       rawws, wdT4, bd, Wr, diagLN);
    hipLaunchKernelGGL(k_embd2, dim3(4096), dim3(256), 0, stream,
                       tty, (const v4u*)table, (const v4u*)diagLN, (v4u*)out2);
}

// Round 2
// 625.162 us; speedup vs baseline: 1.0448x; 1.0058x over previous
//
#include <hip/hip_runtime.h>
#include <hip/hip_bf16.h>

// Problem: VOCAB=30522, TYPES=2, D0=64, D1=768, D2=64, MAXOFF=64, GLOB=64,
// B=8, S=512, EPS=1e-12.
//
// ESTABLISHED (R0-R5 prior session + R6-R7 this session):
//  * Inputs: FP32, setup_inputs() dict order. Outputs: FP32 buffer, compared
//    after bf16 quantization (threshold 0.103). Passing, absmax ~0.008-0.016.
//  * dur_us includes one harness 0xAA poison fill (~350us, 2.2GB) per iter.
//  * R6: k_diagmm occupancy rewrite (512 blocks, barrier-free K-loop,
//    pre-transposed W_diag): 653 -> 629 us. Old diagmm was ~35us, now ~10us.
//  * R7 theory: remaining gap is k_embd2 at ~250us vs 86us write roofline:
//    global-load->nt-store pairs share the vmcnt queue (false serialization)
//    and the 33KB read set thrashes the 32KB L1. Rewrite as LDS->HBM
//    streamer: stage table+diag row in LDS, branch-free rid[] table, hot
//    loop = ds_read_b128 (lgkmcnt) + nt store (vmcnt) -> decoupled counters.
#define S_ 512
#define D1_ 768

typedef unsigned int v4u __attribute__((ext_vector_type(4)));

// out layout (fp32 elements, concatenated in return order):
//   embd0 [8,64,64]      at 0        (32768)
//   embd1 [8,512,768]    at 32768    (3145728)
//   embd2 [8,512,512,64] at 3178496  (134217728)

__device__ __forceinline__ float wsum(float v) {
#pragma unroll
    for (int o = 32; o; o >>= 1) v += __shfl_xor(v, o);
    return v;
}

// ---------------------------------------------------------------------------
// K0: blocks 0..63   -> embd0 = LN(W_glob) broadcast to 8 batches
//     blocks 64..193 -> 130-row LN'd W_rel table (fp32) in ws
//     blocks 194..385-> W_diag transpose: wdT4[g][c] = Wd[c][4g..4g+3]
__global__ __launch_bounds__(64) void k_small(const float* __restrict__ Wg,
                                              const float* __restrict__ Wr,
                                              const float* __restrict__ Wd,
                                              float* __restrict__ out0,
                                              float* __restrict__ table,
                                              float4* __restrict__ wdT4) {
    int t = threadIdx.x;
    int bid = blockIdx.x;
    if (bid >= 194) {
        int g = bid - 194;  // 0..191 : kk block = 4g..4g+3
        float4 v = *(const float4*)(Wd + (size_t)t * D1_ + 4 * g);
        wdT4[g * 64 + t] = v;
        return;
    }
    float v = (bid < 64) ? Wg[bid * 64 + t] : Wr[(bid - 64) * 64 + t];
    float m = wsum(v) * (1.f / 64.f);
    float d = v - m;
    float q = wsum(d * d) * (1.f / 64.f);
    float o = d * rsqrtf(q + 1e-12f);
    if (bid < 64) {
#pragma unroll
        for (int b = 0; b < 8; b++) out0[b * 4096 + bid * 64 + t] = o;
    } else {
        table[(bid - 64) * 64 + t] = o;
    }
}

// ---------------------------------------------------------------------------
// K1: one block per (b,s). raw = W_word[tok]+W_type[ty]+W_abs[s]; out1 =
// LN(raw) fp32; raw also stored fp32 to ws for the diag matmul kernel.
__global__ __launch_bounds__(256) void k_embd1(const int* __restrict__ tok,
                                               const int* __restrict__ tty,
                                               const float* __restrict__ Ww,
                                               const float* __restrict__ Wt,
                                               const float* __restrict__ Wa,
                                               float* __restrict__ out1,
                                               float* __restrict__ rawout) {
    __shared__ float ssum[4], ssq[4];
    int t = threadIdx.x;
    int bs = blockIdx.x;  // b*512 + s
    int s = bs & (S_ - 1);
    size_t wrow = (size_t)tok[bs] * D1_;
    int trow = tty[bs] * D1_;
    int arow = s * D1_;
    float v0 = Ww[wrow + t]       + Wt[trow + t]       + Wa[arow + t];
    float v1 = Ww[wrow + t + 256] + Wt[trow + t + 256] + Wa[arow + t + 256];
    float v2 = Ww[wrow + t + 512] + Wt[trow + t + 512] + Wa[arow + t + 512];
    float ls = v0 + v1 + v2;
    float lq = v0 * v0 + v1 * v1 + v2 * v2;
    float s1 = wsum(ls), q1 = wsum(lq);
    int w = t >> 6;
    if ((t & 63) == 0) { ssum[w] = s1; ssq[w] = q1; }
    __syncthreads();
    float Sa = ssum[0] + ssum[1] + ssum[2] + ssum[3];
    float Qa = ssq[0] + ssq[1] + ssq[2] + ssq[3];
    float mean = Sa * (1.f / 768.f);
    float var = Qa * (1.f / 768.f) - mean * mean;
    float rstd = rsqrtf(var + 1e-12f);
    size_t ob = (size_t)bs * D1_;
    out1[ob + t]       = (v0 - mean) * rstd;
    out1[ob + t + 256] = (v1 - mean) * rstd;
    out1[ob + t + 512] = (v2 - mean) * rstd;
    rawout[ob + t] = v0;
    rawout[ob + t + 256] = v1;
    rawout[ob + t + 512] = v2;
}

// ---------------------------------------------------------------------------
// K1b (R6): diag2 = raw[4096,768] @ Wd[64,768]^T + bd, fused with
// LN(W_rel[0] + diag2) -> diagLN[4096,64]. 512 blocks, 8 rows/block,
// barrier-free K-loop, wdT4 read straight from L2.
__global__ __launch_bounds__(256) void k_diagmm(const float* __restrict__ rawS,
                                                const float4* __restrict__ wdT4,
                                                const float* __restrict__ bd,
                                                const float* __restrict__ Wr,
                                                float* __restrict__ diagLN) {
    __shared__ float rawT[8 * D1_];  // 24 KB
    int t = threadIdx.x;
    int r0 = blockIdx.x * 8;
    for (int x = t; x < 8 * D1_; x += 256)
        rawT[x] = rawS[(size_t)r0 * D1_ + x];
    __syncthreads();
    int c = t & 63, rq = t >> 6;   // col, wave id (wave-uniform)
    const float4* ra4 = (const float4*)&rawT[rq * D1_];        // row rq
    const float4* rb4 = (const float4*)&rawT[(rq + 4) * D1_];  // row rq+4
    float a0 = 0.f, a1 = 0.f;
#pragma unroll 4
    for (int g = 0; g < 192; g++) {
        float4 w = wdT4[g * 64 + c];  // coalesced, L2-hot
        float4 x = ra4[g];            // ds_read_b128 broadcast
        float4 y = rb4[g];
        a0 += x.x * w.x + x.y * w.y + x.z * w.z + x.w * w.w;
        a1 += y.x * w.x + y.y * w.y + y.z * w.z + y.w * w.w;
    }
    float base = bd[c] + Wr[c];  // bias + W_rel row 0 (diagonal base embd)
    {
        float v = a0 + base;
        float mean = wsum(v) * (1.f / 64.f);
        float d = v - mean;
        float q = wsum(d * d) * (1.f / 64.f);
        diagLN[(r0 + rq) * 64 + c] = d * rsqrtf(q + 1e-12f);
    }
    {
        float v = a1 + base;
        float mean = wsum(v) * (1.f / 64.f);
        float d = v - mean;
        float q = wsum(d * d) * (1.f / 64.f);
        diagLN[(r0 + rq + 4) * 64 + c] = d * rsqrtf(q + 1e-12f);
    }
}

// ---------------------------------------------------------------------------
// K2 (R7 rewrite): embd2 pure LDS->HBM streamer. One block per (b,i).
// Preamble: stage the 130 LN'd table rows + this block's diagLN row into LDS
// (33.5KB) and build a branch-free row-id table rid[512] in LDS.
// Hot loop per thread (32 iters): r = rid[j] (ds_read broadcast),
// v = tab[r*16+sub] (ds_read_b128, lgkmcnt), nontemporal store (vmcnt).
// Read and store wait-queues are decoupled -> stores issue at HBM rate.
// rid: diag->130; (i==0,j>0)->128; (i>0,j==0)->129; diff-type->64;
// d=i-j>0 -> 128-min(d,63); d<0 -> min(-d,63).
__global__ __launch_bounds__(256) void k_embd2(const int* __restrict__ tty,
                                               const v4u* __restrict__ table,
                                               const v4u* __restrict__ diagLN,
                                               v4u* __restrict__ out2) {
    __shared__ v4u tab[131 * 16];  // 130 table rows + diag row, 256B each
    __shared__ int rid[S_];
    int t = threadIdx.x;
    int bi = blockIdx.x;  // b*512 + i
    int b = bi >> 9, i = bi & (S_ - 1);
    // stage table rows (coalesced, L2/L3-hot after first blocks)
    for (int x = t; x < 130 * 16; x += 256) tab[x] = table[x];
    if (t < 16) tab[130 * 16 + t] = diagLN[(size_t)bi * 16 + t];
    // branch-free row-id table
    int ti = tty[b * S_ + i];
    for (int j = t; j < S_; j += 256) {
        int tj = tty[b * S_ + j];
        int d = i - j;
        int r;
        if (d == 0)      r = 130;                      // diagonal (incl. 0,0)
        else if (i == 0) r = 128;                      // row 0, j>0
        else if (j == 0) r = 129;                      // col 0, i>0
        else if (tj != ti) r = 64;                     // cross-segment
        else if (d > 0)  r = 128 - (d < 63 ? d : 63);
        else { int nd = -d; r = (nd < 63 ? nd : 63); }
        rid[j] = r;
    }
    __syncthreads();
    int sub = t & 15;       // 16 v4u per 64-fp32 row
    int jbase = t >> 4;     // 16 rows per pass
    size_t obase = (size_t)bi * (S_ * 16);  // v4u index of (b,i,j=0)
#pragma unroll 8
    for (int it = 0; it < 32; it++) {
        int j = it * 16 + jbase;
        int r = rid[j];  // broadcast ds_read (uniform within 16-lane group)
        __builtin_nontemporal_store(tab[r * 16 + sub],
                                    &out2[obase + (size_t)j * 16 + sub]);
    }
}

extern "C" void kernel_launch(void* const* d_in, const int* in_sizes, int n_in,
                              void* d_out, int out_size, void* d_ws, size_t ws_size,
                              hipStream_t stream) {
    // Dict order (confirmed R3/R4): tok(4096) tty(4096) Ww(23440896) Wt(1536)
    // Wa(393216) Wr(8320) Wg(4096) Wd(49152) bd(64).
    const int* tok  = (const int*)d_in[0];
    const int* tty  = (const int*)d_in[1];
    const float* Ww = (const float*)d_in[2];
    const float* Wt = (const float*)d_in[3];
    const float* Wa = (const float*)d_in[4];
    const float* Wr = (const float*)d_in[5];
    const float* Wg = (const float*)d_in[6];
    const float* Wd = (const float*)d_in[7];
    const float* bd = (const float*)d_in[8];

    float* out  = (float*)d_out;
    float* out0 = out;
    float* out1 = out + 32768;
    float* out2 = out + 3178496;

    // ws: table fp32 @0 (33,280B); diagLN fp32 @65536 (1MB); wdT4 @1114112
    // (192KB); raw fp32 @2097152 (12.6MB). Total ~14.7MB.
    float* table  = (float*)d_ws;
    float* diagLN = (float*)((char*)d_ws + 65536);
    float4* wdT4  = (float4*)((char*)d_ws + 1114112);
    float* rawws  = (float*)((char*)d_ws + 2097152);

    hipLaunchKernelGGL(k_small, dim3(386), dim3(64), 0, stream,
                       Wg, Wr, Wd, out0, table, wdT4);
    hipLaunchKernelGGL(k_embd1, dim3(4096), dim3(256), 0, stream,
                       tok, tty, Ww, Wt, Wa, out1, rawws);
    hipLaunchKernelGGL(k_diagmm, dim3(512), dim3(256), 0, stream,
                       rawws, wdT4, bd, Wr, diagLN);
    hipLaunchKernelGGL(k_embd2, dim3(4096), dim3(256), 0, stream,
                       tty, (const v4u*)table, (const v4u*)diagLN, (v4u*)out2);
}